// Round 5
// baseline (204.125 us; speedup 1.0000x reference)
//
#include <hip/hip_runtime.h>
#include <stdint.h>
#include <math.h>

#define NUM_CLASSES 21
#define TOPK 200
#define P_NUM 120000
#define B_NUM 8
#define NBINS 4096
#define CAP 2048
#define PRE_TH 0.9965f
#define CONF_TH 0.05f
#define NMS_TH 0.3f

#define NBLK_PER_B 120
#define ROWS_PER_BLK (P_NUM / NBLK_PER_B)          // 1000
#define SEG_FLOATS (ROWS_PER_BLK * NUM_CLASSES)    // 21000
#define SEG_F4 (SEG_FLOATS / 4)                    // 5250 = 20*256 + 130
#define SLOT_CAP 16
#define NBLK (B_NUM * NBLK_PER_B)                  // 960

// ws layout: [0, NBLK*21*4 = 80640) cnt_T ; [131072, +2.58M) cand_T
// cnt_T  index: (c*B + b)*NBLK_PER_B + seg                (coalesced for select)
// cand_T index: ((c*B + b)*NBLK_PER_B + seg)*SLOT_CAP+sl  (coalesced for select)
#define CAND_OFF 131072

// ---------------------------------------------------------------------------
// Kernel 1: wide prefilter, no global atomics, 8 loads in flight per thread.
// ---------------------------------------------------------------------------
__global__ __launch_bounds__(256) void prefilter_kernel(
        const float* __restrict__ conf,            // [B*P, C]
        unsigned int* __restrict__ cnt_T,
        unsigned long long* __restrict__ cand_T)
{
    __shared__ unsigned int scnt[NUM_CLASSES];
    __shared__ unsigned long long sbuf[NUM_CLASSES][SLOT_CAP];   // 2688 B
    const int blk = blockIdx.x;
    const int b   = blk / NBLK_PER_B;
    const int seg = blk - b * NBLK_PER_B;
    const int t   = threadIdx.x;

    if (t < NUM_CLASSES) scnt[t] = 0u;
    __syncthreads();

    const float4* b4 = (const float4*)(conf +
        ((long long)b * P_NUM + (long long)seg * ROWS_PER_BLK) * NUM_CLASSES);

    // process one float4 (index i in segment) on the rare hit path
    auto process4 = [&](float4 v, int i) {
        #pragma unroll
        for (int e = 0; e < 4; ++e) {
            float s = (e == 0) ? v.x : (e == 1) ? v.y : (e == 2) ? v.z : v.w;
            if (s > PRE_TH) {
                int f = i * 4 + e;
                int r = f / NUM_CLASSES;            // magic-mul
                int c = f - r * NUM_CLASSES;
                if (c != 0) {
                    unsigned int p = (unsigned int)(seg * ROWS_PER_BLK + r);
                    unsigned int pos = atomicAdd(&scnt[c], 1u);
                    if (pos < SLOT_CAP) {
                        sbuf[c][pos] = ((unsigned long long)__float_as_uint(s) << 32)
                                     | (unsigned long long)(0xFFFFFFFFu - p);
                    }
                }
            }
        }
    };

    float4 v[8];
    // two batches of 8 (covers i = t + {0..15}*256), one of 4 ({16..19}), tail
    #pragma unroll
    for (int rep = 0; rep < 2; ++rep) {
        const int base = rep * 8;
        #pragma unroll
        for (int j = 0; j < 8; ++j) v[j] = b4[t + (base + j) * 256];
        float m = -1e30f;
        #pragma unroll
        for (int j = 0; j < 8; ++j)
            m = fmaxf(m, fmaxf(fmaxf(v[j].x, v[j].y), fmaxf(v[j].z, v[j].w)));
        if (m > PRE_TH) {
            #pragma unroll
            for (int j = 0; j < 8; ++j) process4(v[j], t + (base + j) * 256);
        }
    }
    {
        #pragma unroll
        for (int j = 0; j < 4; ++j) v[j] = b4[t + (16 + j) * 256];
        float m = -1e30f;
        #pragma unroll
        for (int j = 0; j < 4; ++j)
            m = fmaxf(m, fmaxf(fmaxf(v[j].x, v[j].y), fmaxf(v[j].z, v[j].w)));
        if (m > PRE_TH) {
            #pragma unroll
            for (int j = 0; j < 4; ++j) process4(v[j], t + (16 + j) * 256);
        }
    }
    if (t < SEG_F4 - 5120) {                        // tail: 130 elements
        float4 w = b4[t + 5120];
        float m = fmaxf(fmaxf(w.x, w.y), fmaxf(w.z, w.w));
        if (m > PRE_TH) process4(w, t + 5120);
    }
    __syncthreads();

    if (t < NUM_CLASSES)
        cnt_T[(t * B_NUM + b) * NBLK_PER_B + seg] = scnt[t];
    for (int idx = t; idx < NUM_CLASSES * SLOT_CAP; idx += 256) {
        int c  = idx >> 4;
        int sl = idx & (SLOT_CAP - 1);
        unsigned int n = scnt[c];
        if (sl < (int)(n < SLOT_CAP ? n : SLOT_CAP)) {
            cand_T[((long long)(c * B_NUM + b) * NBLK_PER_B + seg) * SLOT_CAP + sl] = sbuf[c][sl];
        }
    }
}

// ---------------------------------------------------------------------------
// Kernel 2: per-(b,c) exact top-200 + fused greedy NMS.
// ---------------------------------------------------------------------------
__global__ __launch_bounds__(512) void select_nms_kernel(
        const float* __restrict__ conf,       // [B*P, C]
        const float* __restrict__ loc,        // [B, P, 4]
        const float* __restrict__ prior,      // [P, 4]
        float* __restrict__ out,              // [B, C, TOPK, 5]
        int use_fast,
        const unsigned int* __restrict__ cnt_T,
        const unsigned long long* __restrict__ cand_T) {
    #pragma clang fp contract(off)

    const int c = blockIdx.x;
    const int b = blockIdx.y;
    const int t = threadIdx.x;
    const long long obase = ((long long)(b * NUM_CLASSES + c)) * (TOPK * 5);

    if (c == 0) {
        for (int e = t; e < TOPK * 5; e += 512) out[obase + e] = 0.0f;
        return;
    }

    __shared__ unsigned long long candA[CAP];            // 16384 B
    __shared__ unsigned int hist[NBINS];                 // 16384 B (fallback only)
    __shared__ unsigned long long sorted_k[TOPK];        // 1600 B
    __shared__ float bx[TOPK][4];
    __shared__ float sc[TOPK];
    __shared__ int keepi[TOPK];
    __shared__ unsigned int gsum[64];
    __shared__ unsigned int bcnt[NBLK_PER_B];
    __shared__ unsigned int boff[NBLK_PER_B + 1];
    __shared__ unsigned int s_w0;
    __shared__ int s_cnt2, s_tbin, s_nkeep, s_ok;

    if (t == 0) { s_cnt2 = 0; s_nkeep = 0; s_ok = 1; }
    if (use_fast && t < NBLK_PER_B)
        bcnt[t] = cnt_T[(c * B_NUM + b) * NBLK_PER_B + t];   // coalesced
    __syncthreads();

    if (use_fast) {
        // parallel validity + shfl prefix scan over 120 segment counts
        const int lane = t & 63;
        if (t < NBLK_PER_B && bcnt[t] > SLOT_CAP) s_ok = 0;  // benign race
        if (t < 128) {
            unsigned int x = (t < NBLK_PER_B) ? bcnt[t] : 0u;
            unsigned int incl = x;
            #pragma unroll
            for (int d = 1; d < 64; d <<= 1) {
                unsigned int y = __shfl_up(incl, d, 64);
                if (lane >= d) incl += y;
            }
            if (t < NBLK_PER_B) boff[t] = incl - x;
            if (t == 63) s_w0 = incl;
        }
        __syncthreads();
        if (t >= 64 && t < NBLK_PER_B) boff[t] += s_w0;
        if (t == NBLK_PER_B - 1) boff[NBLK_PER_B] = boff[t] + bcnt[t];
        __syncthreads();
    }

    const bool fast = use_fast && s_ok &&
                      (int)boff[NBLK_PER_B] >= TOPK && (int)boff[NBLK_PER_B] <= CAP;
    int M;

    if (fast) {
        M = (int)boff[NBLK_PER_B];
        const unsigned long long* src =
            cand_T + (long long)(c * B_NUM + b) * NBLK_PER_B * SLOT_CAP;
        for (int idx = t; idx < NBLK_PER_B * SLOT_CAP; idx += 512) {
            int sb = idx >> 4;
            int sl = idx & (SLOT_CAP - 1);
            if (sl < (int)bcnt[sb]) candA[boff[sb] + sl] = src[idx];   // coalesced
        }
        __syncthreads();
    } else {
        // ---- fallback: full strided scan + histogram threshold (guard) -----
        for (int i = t; i < NBINS; i += 512) hist[i] = 0u;
        __syncthreads();
        const float* src = conf + (long long)b * P_NUM * NUM_CLASSES + c;
        for (int p = t; p < P_NUM; p += 512) {
            float s = src[(long long)p * NUM_CLASSES];
            if (s > CONF_TH) {
                int bin = (int)(s * (float)NBINS);
                bin = min(max(bin, 0), NBINS - 1);
                atomicAdd(&hist[bin], 1u);
            }
        }
        __syncthreads();
        if (t < 64) {
            unsigned int a = 0;
            #pragma unroll
            for (int i = 0; i < 64; ++i) a += hist[t * 64 + i];
            gsum[t] = a;
        }
        __syncthreads();
        if (t == 0) {
            int acc = 0;
            int g = 63;
            for (; g >= 0; --g) {
                if (acc + (int)gsum[g] >= TOPK) break;
                acc += (int)gsum[g];
            }
            int tbin = 0;
            if (g >= 0) {
                int bbase = g * 64;
                for (int bi = 63; bi >= 0; --bi) {
                    acc += (int)hist[bbase + bi];
                    if (acc >= TOPK) { tbin = bbase + bi; break; }
                }
            }
            s_tbin = tbin;
        }
        __syncthreads();
        const int tbin = s_tbin;
        for (int p = t; p < P_NUM; p += 512) {
            float s = src[(long long)p * NUM_CLASSES];
            if (s > CONF_TH) {
                int bin = (int)(s * (float)NBINS);
                bin = min(max(bin, 0), NBINS - 1);
                if (bin >= tbin) {
                    int pos = atomicAdd(&s_cnt2, 1);
                    if (pos < CAP) {
                        candA[pos] = ((unsigned long long)__float_as_uint(s) << 32)
                                   | (unsigned long long)(0xFFFFFFFFu - (unsigned int)p);
                    }
                }
            }
        }
        __syncthreads();
        M = min(s_cnt2, CAP);
    }

    // ---- rank-sort: exact top-200 (keys unique: score desc, idx asc) -------
    {
        unsigned long long key[CAP / 512];
        int rnk[CAP / 512];
        #pragma unroll
        for (int k = 0; k < CAP / 512; ++k) {
            int idx = t + k * 512;
            key[k] = (idx < M) ? candA[idx] : 0ULL;
            rnk[k] = 0;
        }
        #pragma unroll 4
        for (int j = 0; j < M; ++j) {
            unsigned long long bj = candA[j];     // LDS broadcast
            #pragma unroll
            for (int k = 0; k < CAP / 512; ++k) rnk[k] += (bj > key[k]) ? 1 : 0;
        }
        #pragma unroll
        for (int k = 0; k < CAP / 512; ++k) {
            int idx = t + k * 512;
            if (idx < M && rnk[k] < TOPK) sorted_k[rnk[k]] = key[k];
        }
    }
    __syncthreads();

    // ---- decode selected boxes --------------------------------------------
    const int nrows = min(M, TOPK);
    if (t < nrows) {
        unsigned long long kk = sorted_k[t];
        float s = __uint_as_float((unsigned int)(kk >> 32));
        unsigned int p = 0xFFFFFFFFu - (unsigned int)kk;
        const float* lp = loc + ((long long)b * P_NUM + p) * 4;
        const float* pp = prior + (long long)p * 4;
        float l0 = lp[0], l1 = lp[1], l2 = lp[2], l3 = lp[3];
        float pcx = pp[0], pcy = pp[1], pw = pp[2], ph = pp[3];
        float cx = pcx + (l0 * 0.1f) * pw;
        float cy = pcy + (l1 * 0.1f) * ph;
        float w  = pw * expf(l2 * 0.2f);
        float h  = ph * expf(l3 * 0.2f);
        float x1 = cx - w * 0.5f;
        float y1 = cy - h * 0.5f;
        float x2 = x1 + w;
        float y2 = y1 + h;
        bx[t][0] = x1; bx[t][1] = y1; bx[t][2] = x2; bx[t][3] = y2;
        sc[t] = s;
    }
    __syncthreads();

    // ---- fused greedy NMS on wave 0: boxes live in registers ---------------
    if (t < 64) {
        float X1[4], Y1[4], X2[4], Y2[4], AR[4];
        unsigned int alive = 0;
        #pragma unroll
        for (int k = 0; k < 4; ++k) {
            int i = t + (k << 6);
            if (i < nrows) {
                X1[k] = bx[i][0]; Y1[k] = bx[i][1];
                X2[k] = bx[i][2]; Y2[k] = bx[i][3];
                AR[k] = (X2[k] - X1[k]) * (Y2[k] - Y1[k]);   // same fp as reference area
                alive |= 1u << k;
            } else { X1[k]=0.f; Y1[k]=0.f; X2[k]=0.f; Y2[k]=0.f; AR[k]=0.f; }
        }
        int nk = 0;
        for (;;) {
            unsigned long long B0 = __ballot(alive & 1u);
            unsigned long long B1 = __ballot(alive & 2u);
            unsigned long long B2 = __ballot(alive & 4u);
            unsigned long long B3 = __ballot(alive & 8u);
            int picked;
            if      (B0) picked =       __builtin_ctzll(B0);
            else if (B1) picked =  64 + __builtin_ctzll(B1);
            else if (B2) picked = 128 + __builtin_ctzll(B2);
            else if (B3) picked = 192 + __builtin_ctzll(B3);
            else break;
            const int owner = picked & 63, kk = picked >> 6;
            float px1 = (kk==0)?X1[0]:(kk==1)?X1[1]:(kk==2)?X1[2]:X1[3];
            float py1 = (kk==0)?Y1[0]:(kk==1)?Y1[1]:(kk==2)?Y1[2]:Y1[3];
            float px2 = (kk==0)?X2[0]:(kk==1)?X2[1]:(kk==2)?X2[2]:X2[3];
            float py2 = (kk==0)?Y2[0]:(kk==1)?Y2[1]:(kk==2)?Y2[2]:Y2[3];
            float pa  = (kk==0)?AR[0]:(kk==1)?AR[1]:(kk==2)?AR[2]:AR[3];
            px1 = __shfl(px1, owner, 64);
            py1 = __shfl(py1, owner, 64);
            px2 = __shfl(px2, owner, 64);
            py2 = __shfl(py2, owner, 64);
            pa  = __shfl(pa , owner, 64);
            if (t == owner) alive &= ~(1u << kk);
            #pragma unroll
            for (int k = 0; k < 4; ++k) {
                if (alive & (1u << k)) {
                    float xx1 = fmaxf(px1, X1[k]);
                    float yy1 = fmaxf(py1, Y1[k]);
                    float xx2 = fminf(px2, X2[k]);
                    float yy2 = fminf(py2, Y2[k]);
                    float ww = fmaxf(xx2 - xx1, 0.0f);
                    float hh = fmaxf(yy2 - yy1, 0.0f);
                    float inter = ww * hh;
                    float uni = (AR[k] - inter) + pa;   // numpy order: area_j - inter + area_i
                    if (inter / uni > NMS_TH) alive &= ~(1u << k);
                }
            }
            if (t == 0) keepi[nk] = picked;
            ++nk;
        }
        if (t == 0) s_nkeep = nk;
    }
    __syncthreads();

    // ---- write output (kept rows in pick order, zero padded) --------------
    int nk = s_nkeep;
    for (int e = t; e < TOPK * 5; e += 512) {
        int r = e / 5, comp = e - r * 5;
        float v = 0.0f;
        if (r < nk) {
            int i = keepi[r];
            v = (comp == 0) ? sc[i] : bx[i][comp - 1];
        }
        out[obase + e] = v;
    }
}

// ---------------------------------------------------------------------------
extern "C" void kernel_launch(void* const* d_in, const int* in_sizes, int n_in,
                              void* d_out, int out_size, void* d_ws, size_t ws_size,
                              hipStream_t stream) {
    const float* loc   = (const float*)d_in[0];
    const float* conf  = (const float*)d_in[1];
    const float* prior = (const float*)d_in[2];
    float* out = (float*)d_out;

    const size_t need = CAND_OFF + (size_t)NBLK * NUM_CLASSES * SLOT_CAP * 8;  // ~2.7 MB
    const int use_fast = (ws_size >= need) ? 1 : 0;
    unsigned int* cnt_T = (unsigned int*)d_ws;
    unsigned long long* cand_T = (unsigned long long*)((char*)d_ws + CAND_OFF);

    if (use_fast) {
        prefilter_kernel<<<NBLK, 256, 0, stream>>>(conf, cnt_T, cand_T);
    }
    dim3 grid(NUM_CLASSES, B_NUM);
    select_nms_kernel<<<grid, 512, 0, stream>>>(conf, loc, prior, out, use_fast,
                                                cnt_T, cand_T);
}